// Round 13
// baseline (189.957 us; speedup 1.0000x reference)
//
#include <hip/hip_runtime.h>
#include <hip/hip_bf16.h>
#include <cstdint>
#include <cstddef>

// ---- problem constants ----
#define NIN   2048
#define RANK  64
#define R2    128      // 2*RANK
#define NROWS 16384    // 8*2048 flattened batch*seq rows

typedef __bf16 bf16x8 __attribute__((ext_vector_type(8)));
typedef float  f32x4  __attribute__((ext_vector_type(4)));
typedef unsigned short u16x8 __attribute__((ext_vector_type(8)));

__device__ __forceinline__ unsigned short f2bf(float f) {
  union { float f; unsigned u; } x; x.f = f;
  return (unsigned short)((x.u + 0x7fffu + ((x.u >> 16) & 1u)) >> 16);
}

// ---- small GEMM tile helper: 16x16 tile t of (A + a*I)(B + b*I), fp32 ----
__device__ __forceinline__ void smallGemm(const float* __restrict__ A,
                                          const float* __restrict__ B,
                                          float* __restrict__ O,
                                          float a, float b, int t, int tid) {
  int i = (t >> 3) * 16 + (tid >> 4);
  int j = (t & 7) * 16 + (tid & 15);
  float acc = 0.f;
#pragma unroll 8
  for (int k = 0; k < R2; ++k) {
    float av = A[i * R2 + k]; if (k == i) av += a;
    float bv = B[k * R2 + j]; if (k == j) bv += b;
    acc += av * bv;
  }
  O[i * R2 + j] = acc;
}

// ---- producer/consumer flags (R7-proven fences; CHEAP polling: tid0 RELAXED) ----
__device__ __forceinline__ void signalCnt(int* c) {
  __syncthreads();                       // all block stores issued+drained (vmcnt0 before barrier)
  if (threadIdx.x == 0) {
    __threadfence();                     // device-scope: writeback to coherence point
    __hip_atomic_fetch_add(c, 1, __ATOMIC_RELEASE, __HIP_MEMORY_SCOPE_AGENT);
  }
}
__device__ __forceinline__ void waitCnt(int* c, int target) {
  if (threadIdx.x == 0) {
    while (__hip_atomic_load(c, __ATOMIC_RELAXED, __HIP_MEMORY_SCOPE_AGENT) < target)
      __builtin_amdgcn_s_sleep(16);
    (void)__hip_atomic_load(c, __ATOMIC_ACQUIRE, __HIP_MEMORY_SCOPE_AGENT);  // inv caches
  }
  __syncthreads();
}

// ---- 1) k_prep: 192 blocks x 512 thr.
//  blocks 0..63:   Mf (frag-order over K=2048; B-operand of k_T1)
//  blocks 64..127: G = J*(M^T M) tile, 2-way K-split + LDS reduce
//  blocks 128..191: Mrf (M rows in frag-order; A-operand of k_OUT)
//  block 0 also zeroes the chain counters (graph replays need fresh flags).
__global__ __launch_bounds__(512) void k_prep(const float* __restrict__ U,
                                              const float* __restrict__ V,
                                              unsigned short* __restrict__ Mf,
                                              unsigned short* __restrict__ Mrf,
                                              float* __restrict__ G,
                                              int* __restrict__ cnt) {
  __shared__ float red[512];
  int b = blockIdx.x, tid = threadIdx.x;
  if (b == 0 && tid < 4) cnt[tid] = 0;
  if (b < 64) {
    int CI = b * 512 + tid;                 // 0..32767
    int lane = CI & 63, J = (CI >> 6) & 63, t = CI >> 12;
    int n = t * 16 + (lane & 15);
    int k0 = J * 32 + (lane >> 4) * 8;
    const float* src = (n < RANK) ? (U + n) : (V + (n - RANK));
    u16x8 h;
#pragma unroll
    for (int e = 0; e < 8; ++e) h[e] = f2bf(src[(size_t)(k0 + e) * RANK]);
    *(u16x8*)(Mf + (size_t)CI * 8) = h;
  } else if (b < 128) {
    int tile = b - 64;                      // 0..63
    int bi = tile >> 3, bj = tile & 7;
    int sub = tid >> 8, t256 = tid & 255;
    int ty = t256 >> 4, tx = t256 & 15;
    int i = bi * 16 + ty, j = bj * 16 + tx;
    const float* Ai = (i < RANK) ? (U + i) : (V + (i - RANK));
    const float* Aj = (j < RANK) ? (U + j) : (V + (j - RANK));
    int k0 = sub * 1024;
    float p0 = 0.f, p1 = 0.f, p2 = 0.f, p3 = 0.f;
#pragma unroll 4
    for (int k = k0; k < k0 + 1024; k += 4) {
      p0 += Ai[(size_t)k * RANK]       * Aj[(size_t)k * RANK];
      p1 += Ai[(size_t)(k + 1) * RANK] * Aj[(size_t)(k + 1) * RANK];
      p2 += Ai[(size_t)(k + 2) * RANK] * Aj[(size_t)(k + 2) * RANK];
      p3 += Ai[(size_t)(k + 3) * RANK] * Aj[(size_t)(k + 3) * RANK];
    }
    red[tid] = (p0 + p1) + (p2 + p3);
    __syncthreads();
    if (sub == 0) {
      float s = red[t256] + red[256 + t256];
      if (i < RANK) G[(i + RANK) * R2 + j] = -s;
      else          G[(i - RANK) * R2 + j] =  s;
    }
  } else {
    // Mrf chunk CI = (t_*4 + J)*64 + lg*16 + lr holds M[t_*16+lr][J*32+lg*8+e]
    int CI = (b - 128) * 512 + tid;         // 0..32767
    int lane = CI & 63, rest = CI >> 6;
    int lr = lane & 15, lg = lane >> 4;
    int J = rest & 3, t_ = rest >> 2;
    int i = t_ * 16 + lr, j0 = J * 32 + lg * 8;
    const float* src = (j0 < RANK) ? (U + (size_t)i * RANK + j0)
                                   : (V + (size_t)i * RANK + (j0 - RANK));
    float4 f0 = *(const float4*)src, f1 = *(const float4*)(src + 4);
    u16x8 h;
    h[0] = f2bf(f0.x); h[1] = f2bf(f0.y); h[2] = f2bf(f0.z); h[3] = f2bf(f0.w);
    h[4] = f2bf(f1.x); h[5] = f2bf(f1.y); h[6] = f2bf(f1.z); h[7] = f2bf(f1.w);
    *(u16x8*)(Mrf + (size_t)CI * 8) = h;
  }
}

// ---- 2) k_T1: blocks 0..575 = polynomial chain (flag-chained, overlaps T1);
//      blocks 576..1599 = T1bf = bf16(input @ M), 16 rows each (verified R12 body).
// Chain safety: at most 512 spinner blocks < 768 resident slots (3/CU x 256 CU),
// producers compute immediately -> deadlock-free regardless of dispatch order.
__global__ __launch_bounds__(256, 3) void k_T1(const float* __restrict__ input,
                                               const unsigned short* __restrict__ Mf,
                                               unsigned short* __restrict__ T1bf,
                                               float* __restrict__ mats,
                                               int* __restrict__ cnt) {
  __shared__ __align__(16) unsigned char lds[33792]; // abuf[w][2] 4KB x8 (32KB) / rbuf [4][16][132] f32 overlay
  if (blockIdx.x < 576) {                    // ---- chain stages s1..s4 ----
    const int cb = blockIdx.x, tid = threadIdx.x;
    float* G_   = mats;
    float* G2_  = mats + 1 * 16384;
    float* G3_  = mats + 2 * 16384;
    float* G4_  = mats + 3 * 16384;
    float* G7_  = mats + 4 * 16384;
    float* G8_  = mats + 5 * 16384;
    float* H12_ = mats + 6 * 16384;
    float* H124_= mats + 7 * 16384;
    float* H_   = mats + 8 * 16384;
    float* G15_ = mats + 9 * 16384;
    if (cb < 64) {                           // s1: G2 = G*G (G ready from node 1)
      smallGemm(G_, G_, G2_, 0.f, 0.f, cb, tid);
      signalCnt(&cnt[0]);
    } else if (cb < 256) {                   // s2
      int t = (cb - 64) & 63, op = (cb - 64) >> 6;
      waitCnt(&cnt[0], 64);
      if (op == 0)      smallGemm(G2_, G2_, G4_,  0.f, 0.f, t, tid);
      else if (op == 1) smallGemm(G2_, G_,  G3_,  0.f, 0.f, t, tid);
      else              smallGemm(G_,  G2_, H12_, 1.f, 1.f, t, tid);
      signalCnt(&cnt[1]);
    } else if (cb < 448) {                   // s3
      int t = (cb - 256) & 63, op = (cb - 256) >> 6;
      waitCnt(&cnt[1], 192);
      if (op == 0)      smallGemm(G4_,  G4_, G8_,   0.f, 0.f, t, tid);
      else if (op == 1) smallGemm(G3_,  G4_, G7_,   0.f, 0.f, t, tid);
      else              smallGemm(H12_, G4_, H124_, 0.f, 1.f, t, tid);
      signalCnt(&cnt[2]);
    } else {                                 // s4 (consumed by node 3 via node boundary)
      int t = (cb - 448) & 63, op = (cb - 448) >> 6;
      waitCnt(&cnt[2], 192);
      if (op == 0) smallGemm(G7_,   G8_, G15_, 0.f, 0.f, t, tid);
      else         smallGemm(H124_, G8_, H_,   0.f, 1.f, t, tid);
    }
    return;
  }
  const int tid = threadIdx.x, lane = tid & 63, w = tid >> 6;
  const int lr = lane & 15, lg = lane >> 4;
  const int row0 = (blockIdx.x - 576) * 16;
  unsigned char* ab0 = lds + w * 8192;

  f32x4 acc[8] = {};
  const float* gbase = input + (size_t)row0 * NIN + w * 512;
  const int Jbase = w * 16;
  float4 s0[4], s1[4];
  bf16x8 bx[8], by[8];

#define T1_SLOAD(KT)                                                          \
  _Pragma("unroll") for (int c = 0; c < 4; ++c) {                             \
    int id = c * 64 + lane; int r = id >> 4, C = id & 15;                     \
    const float* g = gbase + (size_t)r * NIN + (KT) * 128 + C * 8;            \
    s0[c] = *(const float4*)g; s1[c] = *(const float4*)(g + 4);               \
  }
#define T1_SWRITE(BUF)                                                        \
  _Pragma("unroll") for (int c = 0; c < 4; ++c) {                             \
    int id = c * 64 + lane; int r = id >> 4, C = id & 15;                     \
    u16x8 h;                                                                  \
    h[0] = f2bf(s0[c].x); h[1] = f2bf(s0[c].y);                               \
    h[2] = f2bf(s0[c].z); h[3] = f2bf(s0[c].w);                               \
    h[4] = f2bf(s1[c].x); h[5] = f2bf(s1[c].y);                               \
    h[6] = f2bf(s1[c].z); h[7] = f2bf(s1[c].w);                               \
    *(u16x8*)(ab0 + (BUF) * 4096 + r * 256 + ((C ^ (r & 7)) << 4)) = h;       \
  }
#define T1_BLOAD(P, S)                                                        \
  _Pragma("unroll") for (int t = 0; t < 8; ++t)                               \
    P[t] = *(const bf16x8*)(Mf + ((size_t)(t * 64 + Jbase + (S)) * 64 + lane) * 8);

  T1_SLOAD(0);
  T1_SWRITE(0);
  T1_BLOAD(bx, 0);
#pragma unroll
  for (int s = 0; s < 16; ++s) {
    const int kt = s >> 2, sub = s & 3, buf = kt & 1;
    if (sub == 0 && kt < 3) { T1_SLOAD(kt + 1); }
    bf16x8 a = *(const bf16x8*)(ab0 + buf * 4096 + lr * 256 + (((sub * 4 + lg) ^ (lr & 7)) << 4));
    if (s < 15) { if (s & 1) { T1_BLOAD(bx, s + 1); } else { T1_BLOAD(by, s + 1); } }
#pragma unroll
    for (int t = 0; t < 8; ++t) {
      bf16x8 bcur = (s & 1) ? by[t] : bx[t];
      acc[t] = __builtin_amdgcn_mfma_f32_16x16x32_bf16(a, bcur, acc[t], 0, 0, 0);
    }
    if (sub == 2 && kt < 3) { T1_SWRITE(buf ^ 1); }
  }

  // ---- reduce: rbuf[w] = [16 rows][132 pad] f32, overlays abuf ----
  __syncthreads();                           // all waves done with their abuf
  float* rbw = (float*)lds + (size_t)w * 2112;
#pragma unroll
  for (int t = 0; t < 8; ++t) {
    int col = t * 16 + lr;
#pragma unroll
    for (int e = 0; e < 4; ++e) rbw[(lg * 4 + e) * 132 + col] = acc[t][e];
  }
  __syncthreads();
  {
    int r = tid >> 4, c8 = tid & 15;
    f32x4 a0 = {}, a1 = {};
#pragma unroll
    for (int ww = 0; ww < 4; ++ww) {
      const float* p = (const float*)lds + (size_t)ww * 2112 + r * 132 + c8 * 8;
      a0 += *(const f32x4*)p;
      a1 += *(const f32x4*)(p + 4);
    }
    u16x8 o;
#pragma unroll
    for (int i = 0; i < 4; ++i) { o[i] = f2bf(a0[i]); o[4 + i] = f2bf(a1[i]); }
    *(u16x8*)(T1bf + (size_t)(row0 + r) * R2 + c8 * 8) = o;
  }
}

// ---- 3) k_OUT: out = input + T2 @ M^T, with T2 = T1 @ C^T computed in-block.
// C[k][j] = sgn(j)*(2H - G15)[k][jj(j)]. 512 blocks x 256 thr; 32 rows x 2048 cols.
// Wave w owns cols [w*512,(w+1)*512). LDS 43008: cbuf 32KB (prologue) overlaid by
// obuf 4x[32][68] f32 (main); t2buf bf16 [32][128] swz at 34816. 3 blocks/CU.
__global__ __launch_bounds__(256, 3) void k_OUT(const float* __restrict__ input,
                                                const unsigned short* __restrict__ T1bf,
                                                const float* __restrict__ Hm,
                                                const float* __restrict__ G15m,
                                                const unsigned short* __restrict__ Mrf,
                                                float* __restrict__ out) {
  __shared__ __align__(16) unsigned char lds[43008];
  unsigned char* cbuf = lds;
  unsigned char* t2buf = lds + 34816;
  const int tid = threadIdx.x, lane = tid & 63, w = tid >> 6;
  const int lr = lane & 15, lg = lane >> 4;
  const int row0 = blockIdx.x * 32;

  // ---- prologue A: cbuf[k][j-granule swz] = C row-major bf16 ----
#pragma unroll
  for (int it = 0; it < 8; ++it) {
    int id = it * 256 + tid;                 // chunk 0..2047
    int k = id >> 4, j8 = id & 15, j0 = j8 * 8;
    int jj0 = (j0 < RANK) ? j0 + RANK : j0 - RANK;
    float sgn = (j0 < RANK) ? -1.f : 1.f;
    const float* hp = Hm + k * R2 + jj0;
    const float* gp = G15m + k * R2 + jj0;
    float4 h0 = *(const float4*)hp, h1 = *(const float4*)(hp + 4);
    float4 g0 = *(const float4*)gp, g1 = *(const float4*)(gp + 4);
    u16x8 cv;
    cv[0] = f2bf(sgn * (2.f * h0.x - g0.x));
    cv[1] = f2bf(sgn * (2.f * h0.y - g0.y));
    cv[2] = f2bf(sgn * (2.f * h0.z - g0.z));
    cv[3] = f2bf(sgn * (2.f * h0.w - g0.w));
    cv[4] = f2bf(sgn * (2.f * h1.x - g1.x));
    cv[5] = f2bf(sgn * (2.f * h1.y - g1.y));
    cv[6] = f2bf(sgn * (2.f * h1.z - g1.z));
    cv[7] = f2bf(sgn * (2.f * h1.w - g1.w));
    *(u16x8*)(cbuf + k * 256 + ((j8 ^ (k & 7)) << 4)) = cv;
  }
  // T1 frags (B operand of T2-mfma): lane lr -> T1 row row0+R*16+lr
  bf16x8 t1f[2][4];
#pragma unroll
  for (int R = 0; R < 2; ++R)
#pragma unroll
    for (int J = 0; J < 4; ++J)
      t1f[R][J] = *(const bf16x8*)(T1bf + (size_t)(row0 + R * 16 + lr) * R2 + J * 32 + lg * 8);
  __syncthreads();                           // cbuf ready

  // ---- prologue B: T2[r][kc] = sum_j T1[r][j] C[kc][j]; wave w: kc-tiles {2w,2w+1} ----
#pragma unroll
  for (int kk = 0; kk < 2; ++kk) {
    int kct = w * 2 + kk;
    int kc = kct * 16 + lr;                  // C row this lane supplies
    f32x4 a2[2] = {};
#pragma unroll
    for (int jkt = 0; jkt < 4; ++jkt) {
      bf16x8 cf = *(const bf16x8*)(cbuf + kc * 256 + (((jkt * 4 + lg) ^ (kc & 7)) << 4));
#pragma unroll
      for (int R = 0; R < 2; ++R)
        a2[R] = __builtin_amdgcn_mfma_f32_16x16x32_bf16(cf, t1f[R][jkt], a2[R], 0, 0, 0);
    }
    // acc layout: col=lr -> r_local, row=lg*4+e -> kc = kct*16+lg*4+e
#pragma unroll
    for (int R = 0; R < 2; ++R) {
      int r = R * 16 + lr;
      ushort4 p;
      p.x = f2bf(a2[R][0]); p.y = f2bf(a2[R][1]);
      p.z = f2bf(a2[R][2]); p.w = f2bf(a2[R][3]);
      int gran = kct * 2 + (lg >> 1), off = (lg & 1) * 8;
      *(ushort4*)(t2buf + r * 256 + ((gran ^ (r & 7)) << 4) + off) = p;
    }
  }
  __syncthreads();                           // t2buf ready; cbuf dead (obuf may overlay)

  // bq = T2 frags: lane lr -> row R*16+lr, k-slice J*32+lg*8
  bf16x8 bq[2][4];
#pragma unroll
  for (int R = 0; R < 2; ++R)
#pragma unroll
    for (int J = 0; J < 4; ++J) {
      int row = R * 16 + lr;
      bq[R][J] = *(const bf16x8*)(t2buf + row * 256 + (((J * 4 + lg) ^ (row & 7)) << 4));
    }

  // ---- main loop: verified epilogue shape (64-col groups, [32][68] obuf) ----
  float* obufw = (float*)(lds + w * 8704);   // per-wave [32][68] f32
  bf16x8 xd[4], yd[4];
#define O_DLOAD(P, TTI)                                                       \
  _Pragma("unroll") for (int J = 0; J < 4; ++J)                               \
    P[J] = *(const bf16x8*)(Mrf + ((size_t)((w * 32 + (TTI)) * 4 + J) * 64 + lane) * 8);

  O_DLOAD(xd, 0);
#pragma unroll
  for (int g = 0; g < 8; ++g) {
#pragma unroll
    for (int tt = 0; tt < 4; ++tt) {
      const int tti = g * 4 + tt;
      if (tti < 31) { if (tti & 1) { O_DLOAD(xd, tti + 1); } else { O_DLOAD(yd, tti + 1); } }
#pragma unroll
      for (int R = 0; R < 2; ++R) {
        f32x4 o = {};
#pragma unroll
        for (int J = 0; J < 4; ++J) {
          bf16x8 d = (tti & 1) ? yd[J] : xd[J];
          o = __builtin_amdgcn_mfma_f32_16x16x32_bf16(d, bq[R][J], o, 0, 0, 0);
        }
        *(f32x4*)&obufw[(R * 16 + lr) * 68 + tt * 16 + lg * 4] = o;
      }
    }
#pragma unroll
    for (int c = 0; c < 8; ++c) {
      int id = c * 64 + lane, r = id >> 4, cc = id & 15;
      f32x4 v = *(const f32x4*)&obufw[r * 68 + cc * 4];
      int grow = row0 + r, gcol = w * 512 + g * 64 + cc * 4;
      float4 inv = *(const float4*)(input + (size_t)grow * NIN + gcol);
      float4 res = { v[0] + inv.x, v[1] + inv.y, v[2] + inv.z, v[3] + inv.w };
      *(float4*)(out + (size_t)grow * NIN + gcol) = res;
    }
  }
}

extern "C" void kernel_launch(void* const* d_in, const int* in_sizes, int n_in,
                              void* d_out, int out_size, void* d_ws, size_t ws_size,
                              hipStream_t stream) {
  const float* input = (const float*)d_in[0];
  const float* U     = (const float*)d_in[1];
  const float* V     = (const float*)d_in[2];
  float* out = (float*)d_out;
  char* ws = (char*)d_ws;

  // workspace layout
  float* mats = (float*)ws;                       // 10 x 128x128 fp32 = 640 KB
  float* G   = mats + 0 * 16384;
  float* H   = mats + 8 * 16384;
  float* G15 = mats + 9 * 16384;
  unsigned short* Mf   = (unsigned short*)(ws + 10 * 65536);              // 512 KB frag-order M (K=2048)
  unsigned short* Mrf  = (unsigned short*)(ws + 10 * 65536 + 524288);     // 512 KB frag-order M rows (K=128)
  unsigned short* T1bf = (unsigned short*)(ws + 10 * 65536 + 2 * 524288); // 4 MB
  int* cnt = (int*)(ws + 10 * 65536 + 2 * 524288 + 4194304);              // 4 flags

  k_prep<<<192, 512, 0, stream>>>(U, V, Mf, Mrf, G, cnt);
  k_T1<<<1600, 256, 0, stream>>>(input, Mf, T1bf, mats, cnt);   // chain (576) + T1 (1024)
  k_OUT<<<512, 256, 0, stream>>>(input, T1bf, H, G15, Mrf, out);
}

// Round 14
// 175.579 us; speedup vs baseline: 1.0819x; 1.0819x over previous
//
#include <hip/hip_runtime.h>
#include <hip/hip_bf16.h>
#include <cstdint>
#include <cstddef>

// ---- problem constants ----
#define NIN   2048
#define RANK  64
#define R2    128      // 2*RANK
#define NROWS 16384    // 8*2048 flattened batch*seq rows

typedef __bf16 bf16x8 __attribute__((ext_vector_type(8)));
typedef float  f32x4  __attribute__((ext_vector_type(4)));
typedef unsigned short u16x8 __attribute__((ext_vector_type(8)));

__device__ __forceinline__ unsigned short f2bf(float f) {
  union { float f; unsigned u; } x; x.f = f;
  return (unsigned short)((x.u + 0x7fffu + ((x.u >> 16) & 1u)) >> 16);
}

// ---- small GEMM tile helper: 16x16 tile t of (A + a*I)(B + b*I), fp32 ----
__device__ __forceinline__ void smallGemm(const float* __restrict__ A,
                                          const float* __restrict__ B,
                                          float* __restrict__ O,
                                          float a, float b, int t, int tid) {
  int i = (t >> 3) * 16 + (tid >> 4);
  int j = (t & 7) * 16 + (tid & 15);
  float acc = 0.f;
#pragma unroll 8
  for (int k = 0; k < R2; ++k) {
    float av = A[i * R2 + k]; if (k == i) av += a;
    float bv = B[k * R2 + j]; if (k == j) bv += b;
    acc += av * bv;
  }
  O[i * R2 + j] = acc;
}

// ---- producer/consumer flags (R13-verified fences; tid0 RELAXED poll only) ----
__device__ __forceinline__ void signalCnt(int* c) {
  __syncthreads();                       // all block stores drained (vmcnt0 before barrier)
  if (threadIdx.x == 0) {
    __threadfence();                     // device-scope writeback
    __hip_atomic_fetch_add(c, 1, __ATOMIC_RELEASE, __HIP_MEMORY_SCOPE_AGENT);
  }
}
__device__ __forceinline__ void waitCnt(int* c, int target) {
  if (threadIdx.x == 0) {
    while (__hip_atomic_load(c, __ATOMIC_RELAXED, __HIP_MEMORY_SCOPE_AGENT) < target)
      __builtin_amdgcn_s_sleep(16);
    (void)__hip_atomic_load(c, __ATOMIC_ACQUIRE, __HIP_MEMORY_SCOPE_AGENT);  // inv caches
  }
  __syncthreads();
}

// ---- 1) k_prep: 480 blocks x 512 thr. Everything before the big GEMMs.
//  b 0..63   : Mf (frag-order over K=2048; B-operand of k_T1)
//  b 64..127 : G = J*(M^T M) tile (2-way K-split + LDS reduce) -> signal cnt[0]
//  b 128..191: Mrf (M rows frag-order; A-operand of k_OUT)
//  b 192..223: s1 G2=G*G          (wait cnt[0]=64,  signal cnt[1]; 2 tiles/block)
//  b 224..319: s2 G4,G3,H12       (wait cnt[1]=32,  signal cnt[2])
//  b 320..415: s3 G8,G7,H124      (wait cnt[2]=96,  signal cnt[3])
//  b 416..479: s4 G15,H           (wait cnt[3]=96)
// Deadlock-free: 480 blocks x 8 waves, ~2KB LDS, low VGPR -> >=4 blocks/CU
// resident capacity (1024) > 480, so producers always run while consumers spin.
__global__ __launch_bounds__(512) void k_prep(const float* __restrict__ U,
                                              const float* __restrict__ V,
                                              unsigned short* __restrict__ Mf,
                                              unsigned short* __restrict__ Mrf,
                                              float* __restrict__ mats,
                                              int* __restrict__ cnt) {
  __shared__ float red[512];
  int b = blockIdx.x, tid = threadIdx.x;
  float* G_   = mats;
  float* G2_  = mats + 1 * 16384;
  float* G3_  = mats + 2 * 16384;
  float* G4_  = mats + 3 * 16384;
  float* G7_  = mats + 4 * 16384;
  float* G8_  = mats + 5 * 16384;
  float* H12_ = mats + 6 * 16384;
  float* H124_= mats + 7 * 16384;
  float* H_   = mats + 8 * 16384;
  float* G15_ = mats + 9 * 16384;

  if (b < 64) {
    int CI = b * 512 + tid;                 // 0..32767
    int lane = CI & 63, J = (CI >> 6) & 63, t = CI >> 12;
    int n = t * 16 + (lane & 15);
    int k0 = J * 32 + (lane >> 4) * 8;
    const float* src = (n < RANK) ? (U + n) : (V + (n - RANK));
    u16x8 h;
#pragma unroll
    for (int e = 0; e < 8; ++e) h[e] = f2bf(src[(size_t)(k0 + e) * RANK]);
    *(u16x8*)(Mf + (size_t)CI * 8) = h;
  } else if (b < 128) {
    int tile = b - 64;                      // 0..63
    int bi = tile >> 3, bj = tile & 7;
    int sub = tid >> 8, t256 = tid & 255;
    int ty = t256 >> 4, tx = t256 & 15;
    int i = bi * 16 + ty, j = bj * 16 + tx;
    const float* Ai = (i < RANK) ? (U + i) : (V + (i - RANK));
    const float* Aj = (j < RANK) ? (U + j) : (V + (j - RANK));
    int k0 = sub * 1024;
    float p0 = 0.f, p1 = 0.f, p2 = 0.f, p3 = 0.f;
#pragma unroll 4
    for (int k = k0; k < k0 + 1024; k += 4) {
      p0 += Ai[(size_t)k * RANK]       * Aj[(size_t)k * RANK];
      p1 += Ai[(size_t)(k + 1) * RANK] * Aj[(size_t)(k + 1) * RANK];
      p2 += Ai[(size_t)(k + 2) * RANK] * Aj[(size_t)(k + 2) * RANK];
      p3 += Ai[(size_t)(k + 3) * RANK] * Aj[(size_t)(k + 3) * RANK];
    }
    red[tid] = (p0 + p1) + (p2 + p3);
    __syncthreads();
    if (sub == 0) {
      float s = red[t256] + red[256 + t256];
      if (i < RANK) G_[(i + RANK) * R2 + j] = -s;
      else          G_[(i - RANK) * R2 + j] =  s;
    }
    signalCnt(&cnt[0]);
  } else if (b < 192) {
    // Mrf chunk CI = (t_*4 + J)*64 + lg*16 + lr holds M[t_*16+lr][J*32+lg*8+e]
    int CI = (b - 128) * 512 + tid;         // 0..32767
    int lane = CI & 63, rest = CI >> 6;
    int lr = lane & 15, lg = lane >> 4;
    int J = rest & 3, t_ = rest >> 2;
    int i = t_ * 16 + lr, j0 = J * 32 + lg * 8;
    const float* src = (j0 < RANK) ? (U + (size_t)i * RANK + j0)
                                   : (V + (size_t)i * RANK + (j0 - RANK));
    float4 f0 = *(const float4*)src, f1 = *(const float4*)(src + 4);
    u16x8 h;
    h[0] = f2bf(f0.x); h[1] = f2bf(f0.y); h[2] = f2bf(f0.z); h[3] = f2bf(f0.w);
    h[4] = f2bf(f1.x); h[5] = f2bf(f1.y); h[6] = f2bf(f1.z); h[7] = f2bf(f1.w);
    *(u16x8*)(Mrf + (size_t)CI * 8) = h;
  } else {
    // chain stages; each 512-thr block does 2 tiles (tid>>8 picks tile, tid&255 local)
    int t2 = tid >> 8, tl = tid & 255;
    if (b < 224) {                          // s1: tiles 0..63 of G2 = G*G
      waitCnt(&cnt[0], 64);
      smallGemm(G_, G_, G2_, 0.f, 0.f, (b - 192) * 2 + t2, tl);
      signalCnt(&cnt[1]);
    } else if (b < 320) {                   // s2: 192 tiles
      waitCnt(&cnt[1], 32);
      int tile = (b - 224) * 2 + t2, op = tile >> 6, t = tile & 63;
      if (op == 0)      smallGemm(G2_, G2_, G4_,  0.f, 0.f, t, tl);
      else if (op == 1) smallGemm(G2_, G_,  G3_,  0.f, 0.f, t, tl);
      else              smallGemm(G_,  G2_, H12_, 1.f, 1.f, t, tl);
      signalCnt(&cnt[2]);
    } else if (b < 416) {                   // s3: 192 tiles
      waitCnt(&cnt[2], 96);
      int tile = (b - 320) * 2 + t2, op = tile >> 6, t = tile & 63;
      if (op == 0)      smallGemm(G4_,  G4_, G8_,   0.f, 0.f, t, tl);
      else if (op == 1) smallGemm(G3_,  G4_, G7_,   0.f, 0.f, t, tl);
      else              smallGemm(H12_, G4_, H124_, 0.f, 1.f, t, tl);
      signalCnt(&cnt[3]);
    } else {                                // s4: 128 tiles (H, G15 -> node 3)
      waitCnt(&cnt[3], 96);
      int tile = (b - 416) * 2 + t2, op = tile >> 6, t = tile & 63;
      if (op == 0) smallGemm(G7_,   G8_, G15_, 0.f, 0.f, t, tl);
      else         smallGemm(H124_, G8_, H_,   0.f, 1.f, t, tl);
    }
  }
}

// ---- 2) k_T1: T1bf = bf16(input @ M). 1024 blocks of 16 rows (verified R12 body).
// Wave w owns K-range [w*512,(w+1)*512), 4 K-steps of 128, double-buffered 4KB abuf.
__global__ __launch_bounds__(256, 3) void k_T1(const float* __restrict__ input,
                                               const unsigned short* __restrict__ Mf,
                                               unsigned short* __restrict__ T1bf) {
  __shared__ __align__(16) unsigned char lds[33792]; // abuf[w][2] 4KB x8 (32KB) / rbuf [4][16][132] f32 overlay
  const int tid = threadIdx.x, lane = tid & 63, w = tid >> 6;
  const int lr = lane & 15, lg = lane >> 4;
  const int row0 = blockIdx.x * 16;
  unsigned char* ab0 = lds + w * 8192;

  f32x4 acc[8] = {};
  const float* gbase = input + (size_t)row0 * NIN + w * 512;
  const int Jbase = w * 16;
  float4 s0[4], s1[4];
  bf16x8 bx[8], by[8];

#define T1_SLOAD(KT)                                                          \
  _Pragma("unroll") for (int c = 0; c < 4; ++c) {                             \
    int id = c * 64 + lane; int r = id >> 4, C = id & 15;                     \
    const float* g = gbase + (size_t)r * NIN + (KT) * 128 + C * 8;            \
    s0[c] = *(const float4*)g; s1[c] = *(const float4*)(g + 4);               \
  }
#define T1_SWRITE(BUF)                                                        \
  _Pragma("unroll") for (int c = 0; c < 4; ++c) {                             \
    int id = c * 64 + lane; int r = id >> 4, C = id & 15;                     \
    u16x8 h;                                                                  \
    h[0] = f2bf(s0[c].x); h[1] = f2bf(s0[c].y);                               \
    h[2] = f2bf(s0[c].z); h[3] = f2bf(s0[c].w);                               \
    h[4] = f2bf(s1[c].x); h[5] = f2bf(s1[c].y);                               \
    h[6] = f2bf(s1[c].z); h[7] = f2bf(s1[c].w);                               \
    *(u16x8*)(ab0 + (BUF) * 4096 + r * 256 + ((C ^ (r & 7)) << 4)) = h;       \
  }
#define T1_BLOAD(P, S)                                                        \
  _Pragma("unroll") for (int t = 0; t < 8; ++t)                               \
    P[t] = *(const bf16x8*)(Mf + ((size_t)(t * 64 + Jbase + (S)) * 64 + lane) * 8);

  T1_SLOAD(0);
  T1_SWRITE(0);
  T1_BLOAD(bx, 0);
#pragma unroll
  for (int s = 0; s < 16; ++s) {
    const int kt = s >> 2, sub = s & 3, buf = kt & 1;
    if (sub == 0 && kt < 3) { T1_SLOAD(kt + 1); }
    bf16x8 a = *(const bf16x8*)(ab0 + buf * 4096 + lr * 256 + (((sub * 4 + lg) ^ (lr & 7)) << 4));
    if (s < 15) { if (s & 1) { T1_BLOAD(bx, s + 1); } else { T1_BLOAD(by, s + 1); } }
#pragma unroll
    for (int t = 0; t < 8; ++t) {
      bf16x8 bcur = (s & 1) ? by[t] : bx[t];
      acc[t] = __builtin_amdgcn_mfma_f32_16x16x32_bf16(a, bcur, acc[t], 0, 0, 0);
    }
    if (sub == 2 && kt < 3) { T1_SWRITE(buf ^ 1); }
  }

  // ---- reduce: rbuf[w] = [16 rows][132 pad] f32, overlays abuf ----
  __syncthreads();                           // all waves done with their abuf
  float* rbw = (float*)lds + (size_t)w * 2112;
#pragma unroll
  for (int t = 0; t < 8; ++t) {
    int col = t * 16 + lr;
#pragma unroll
    for (int e = 0; e < 4; ++e) rbw[(lg * 4 + e) * 132 + col] = acc[t][e];
  }
  __syncthreads();
  {
    int r = tid >> 4, c8 = tid & 15;
    f32x4 a0 = {}, a1 = {};
#pragma unroll
    for (int ww = 0; ww < 4; ++ww) {
      const float* p = (const float*)lds + (size_t)ww * 2112 + r * 132 + c8 * 8;
      a0 += *(const f32x4*)p;
      a1 += *(const f32x4*)(p + 4);
    }
    u16x8 o;
#pragma unroll
    for (int i = 0; i < 4; ++i) { o[i] = f2bf(a0[i]); o[4 + i] = f2bf(a1[i]); }
    *(u16x8*)(T1bf + (size_t)(row0 + r) * R2 + c8 * 8) = o;
  }
}

// ---- 3) k_OUT: out = input + T2 @ M^T, with T2 = T1 @ C^T computed in-block.
// C[k][j] = sgn(j)*(2H - G15)[k][jj(j)]. 512 blocks x 256 thr; 32 rows x 2048 cols.
// Wave w owns cols [w*512,(w+1)*512). LDS 43008: cbuf 32KB (prologue) overlaid by
// obuf 4x[32][68] f32 (main); t2buf bf16 [32][128] swz at 34816. 3 blocks/CU.
__global__ __launch_bounds__(256, 3) void k_OUT(const float* __restrict__ input,
                                                const unsigned short* __restrict__ T1bf,
                                                const float* __restrict__ Hm,
                                                const float* __restrict__ G15m,
                                                const unsigned short* __restrict__ Mrf,
                                                float* __restrict__ out) {
  __shared__ __align__(16) unsigned char lds[43008];
  unsigned char* cbuf = lds;
  unsigned char* t2buf = lds + 34816;
  const int tid = threadIdx.x, lane = tid & 63, w = tid >> 6;
  const int lr = lane & 15, lg = lane >> 4;
  const int row0 = blockIdx.x * 32;

  // ---- prologue A: cbuf[k][j-granule swz] = C row-major bf16 ----
#pragma unroll
  for (int it = 0; it < 8; ++it) {
    int id = it * 256 + tid;                 // chunk 0..2047
    int k = id >> 4, j8 = id & 15, j0 = j8 * 8;
    int jj0 = (j0 < RANK) ? j0 + RANK : j0 - RANK;
    float sgn = (j0 < RANK) ? -1.f : 1.f;
    const float* hp = Hm + k * R2 + jj0;
    const float* gp = G15m + k * R2 + jj0;
    float4 h0 = *(const float4*)hp, h1 = *(const float4*)(hp + 4);
    float4 g0 = *(const float4*)gp, g1 = *(const float4*)(gp + 4);
    u16x8 cv;
    cv[0] = f2bf(sgn * (2.f * h0.x - g0.x));
    cv[1] = f2bf(sgn * (2.f * h0.y - g0.y));
    cv[2] = f2bf(sgn * (2.f * h0.z - g0.z));
    cv[3] = f2bf(sgn * (2.f * h0.w - g0.w));
    cv[4] = f2bf(sgn * (2.f * h1.x - g1.x));
    cv[5] = f2bf(sgn * (2.f * h1.y - g1.y));
    cv[6] = f2bf(sgn * (2.f * h1.z - g1.z));
    cv[7] = f2bf(sgn * (2.f * h1.w - g1.w));
    *(u16x8*)(cbuf + k * 256 + ((j8 ^ (k & 7)) << 4)) = cv;
  }
  // T1 frags (B operand of T2-mfma): lane lr -> T1 row row0+R*16+lr
  bf16x8 t1f[2][4];
#pragma unroll
  for (int R = 0; R < 2; ++R)
#pragma unroll
    for (int J = 0; J < 4; ++J)
      t1f[R][J] = *(const bf16x8*)(T1bf + (size_t)(row0 + R * 16 + lr) * R2 + J * 32 + lg * 8);
  __syncthreads();                           // cbuf ready

  // ---- prologue B: T2[r][kc] = sum_j T1[r][j] C[kc][j]; wave w: kc-tiles {2w,2w+1} ----
#pragma unroll
  for (int kk = 0; kk < 2; ++kk) {
    int kct = w * 2 + kk;
    int kc = kct * 16 + lr;                  // C row this lane supplies
    f32x4 a2[2] = {};
#pragma unroll
    for (int jkt = 0; jkt < 4; ++jkt) {
      bf16x8 cf = *(const bf16x8*)(cbuf + kc * 256 + (((jkt * 4 + lg) ^ (kc & 7)) << 4));
#pragma unroll
      for (int R = 0; R < 2; ++R)
        a2[R] = __builtin_amdgcn_mfma_f32_16x16x32_bf16(cf, t1f[R][jkt], a2[R], 0, 0, 0);
    }
    // acc layout: col=lr -> r_local, row=lg*4+e -> kc = kct*16+lg*4+e
#pragma unroll
    for (int R = 0; R < 2; ++R) {
      int r = R * 16 + lr;
      ushort4 p;
      p.x = f2bf(a2[R][0]); p.y = f2bf(a2[R][1]);
      p.z = f2bf(a2[R][2]); p.w = f2bf(a2[R][3]);
      int gran = kct * 2 + (lg >> 1), off = (lg & 1) * 8;
      *(ushort4*)(t2buf + r * 256 + ((gran ^ (r & 7)) << 4) + off) = p;
    }
  }
  __syncthreads();                           // t2buf ready; cbuf dead (obuf may overlay)

  // bq = T2 frags: lane lr -> row R*16+lr, k-slice J*32+lg*8
  bf16x8 bq[2][4];
#pragma unroll
  for (int R = 0; R < 2; ++R)
#pragma unroll
    for (int J = 0; J < 4; ++J) {
      int row = R * 16 + lr;
      bq[R][J] = *(const bf16x8*)(t2buf + row * 256 + (((J * 4 + lg) ^ (row & 7)) << 4));
    }

  // ---- main loop: verified epilogue shape (64-col groups, [32][68] obuf) ----
  float* obufw = (float*)(lds + w * 8704);   // per-wave [32][68] f32
  bf16x8 xd[4], yd[4];
#define O_DLOAD(P, TTI)                                                       \
  _Pragma("unroll") for (int J = 0; J < 4; ++J)                               \
    P[J] = *(const bf16x8*)(Mrf + ((size_t)((w * 32 + (TTI)) * 4 + J) * 64 + lane) * 8);

  O_DLOAD(xd, 0);
#pragma unroll
  for (int g = 0; g < 8; ++g) {
#pragma unroll
    for (int tt = 0; tt < 4; ++tt) {
      const int tti = g * 4 + tt;
      if (tti < 31) { if (tti & 1) { O_DLOAD(xd, tti + 1); } else { O_DLOAD(yd, tti + 1); } }
#pragma unroll
      for (int R = 0; R < 2; ++R) {
        f32x4 o = {};
#pragma unroll
        for (int J = 0; J < 4; ++J) {
          bf16x8 d = (tti & 1) ? yd[J] : xd[J];
          o = __builtin_amdgcn_mfma_f32_16x16x32_bf16(d, bq[R][J], o, 0, 0, 0);
        }
        *(f32x4*)&obufw[(R * 16 + lr) * 68 + tt * 16 + lg * 4] = o;
      }
    }
#pragma unroll
    for (int c = 0; c < 8; ++c) {
      int id = c * 64 + lane, r = id >> 4, cc = id & 15;
      f32x4 v = *(const f32x4*)&obufw[r * 68 + cc * 4];
      int grow = row0 + r, gcol = w * 512 + g * 64 + cc * 4;
      float4 inv = *(const float4*)(input + (size_t)grow * NIN + gcol);
      float4 res = { v[0] + inv.x, v[1] + inv.y, v[2] + inv.z, v[3] + inv.w };
      *(float4*)(out + (size_t)grow * NIN + gcol) = res;
    }
  }
}

extern "C" void kernel_launch(void* const* d_in, const int* in_sizes, int n_in,
                              void* d_out, int out_size, void* d_ws, size_t ws_size,
                              hipStream_t stream) {
  const float* input = (const float*)d_in[0];
  const float* U     = (const float*)d_in[1];
  const float* V     = (const float*)d_in[2];
  float* out = (float*)d_out;
  char* ws = (char*)d_ws;

  // workspace layout
  float* mats = (float*)ws;                       // 10 x 128x128 fp32 = 640 KB
  float* H   = mats + 8 * 16384;
  float* G15 = mats + 9 * 16384;
  unsigned short* Mf   = (unsigned short*)(ws + 10 * 65536);              // 512 KB frag-order M (K=2048)
  unsigned short* Mrf  = (unsigned short*)(ws + 10 * 65536 + 524288);     // 512 KB frag-order M rows (K=128)
  unsigned short* T1bf = (unsigned short*)(ws + 10 * 65536 + 2 * 524288); // 4 MB
  int* cnt = (int*)(ws + 10 * 65536 + 2 * 524288 + 4194304);              // 4 flags

  hipMemsetAsync(cnt, 0, 16, stream);             // fresh flags per replay (16B fill ~ free, R6)
  k_prep<<<480, 512, 0, stream>>>(U, V, Mf, Mrf, mats, cnt);  // + full polynomial chain
  k_T1<<<1024, 256, 0, stream>>>(input, Mf, T1bf);
  k_OUT<<<512, 256, 0, stream>>>(input, T1bf, H, G15, Mrf, out);
}

// Round 15
// 149.143 us; speedup vs baseline: 1.2737x; 1.1773x over previous
//
#include <hip/hip_runtime.h>
#include <hip/hip_bf16.h>
#include <cstdint>
#include <cstddef>

// ---- problem constants ----
#define NIN   2048
#define RANK  64
#define R2    128      // 2*RANK
#define NROWS 16384    // 8*2048 flattened batch*seq rows

typedef __bf16 bf16x8 __attribute__((ext_vector_type(8)));
typedef float  f32x4  __attribute__((ext_vector_type(4)));
typedef unsigned short u16x8 __attribute__((ext_vector_type(8)));

__device__ __forceinline__ unsigned short f2bf(float f) {
  union { float f; unsigned u; } x; x.f = f;
  return (unsigned short)((x.u + 0x7fffu + ((x.u >> 16) & 1u)) >> 16);
}

// ---- small GEMM tile helper: 16x16 tile t of (A + a*I)(B + b*I), fp32 ----
// If Obf != nullptr, also scatter bf16(acc) in TRANSPOSED frag-order:
// chunk (t_*4+J)*64+lg*16+lr holds O^T[t_*16+lr][J*32+lg*8+e]  (k_D/Mrf pattern)
__device__ __forceinline__ void smallGemm(const float* __restrict__ A,
                                          const float* __restrict__ B,
                                          float* __restrict__ O,
                                          unsigned short* __restrict__ Obf,
                                          float a, float b, int t, int tid) {
  int i = (t >> 3) * 16 + (tid >> 4);
  int j = (t & 7) * 16 + (tid & 15);
  float acc = 0.f;
#pragma unroll 8
  for (int k = 0; k < R2; ++k) {
    float av = A[i * R2 + k]; if (k == i) av += a;
    float bv = B[k * R2 + j]; if (k == j) bv += b;
    acc += av * bv;
  }
  O[i * R2 + j] = acc;
  if (Obf) {
    // O^T row = j, col = i
    int t_ = j >> 4, lr = j & 15, J = i >> 5, lg = (i >> 3) & 3, e = i & 7;
    Obf[((size_t)(t_ * 4 + J) * 64 + lg * 16 + lr) * 8 + e] = f2bf(acc);
  }
}

// ---- 1) k_prep: 192 blocks x 512 thr.  (verified R12 code)
//  blocks 0..63:   Mf (frag-order over K=2048; B-operand of k_T1)
//  blocks 64..127: G = J*(M^T M) tile, 2-way K-split + LDS reduce
//  blocks 128..191: Mrf (M rows in frag-order; A-operand of k_OUT)
__global__ __launch_bounds__(512) void k_prep(const float* __restrict__ U,
                                              const float* __restrict__ V,
                                              unsigned short* __restrict__ Mf,
                                              unsigned short* __restrict__ Mrf,
                                              float* __restrict__ G) {
  __shared__ float red[512];
  int b = blockIdx.x, tid = threadIdx.x;
  if (b < 64) {
    int CI = b * 512 + tid;                 // 0..32767
    int lane = CI & 63, J = (CI >> 6) & 63, t = CI >> 12;
    int n = t * 16 + (lane & 15);
    int k0 = J * 32 + (lane >> 4) * 8;
    const float* src = (n < RANK) ? (U + n) : (V + (n - RANK));
    u16x8 h;
#pragma unroll
    for (int e = 0; e < 8; ++e) h[e] = f2bf(src[(size_t)(k0 + e) * RANK]);
    *(u16x8*)(Mf + (size_t)CI * 8) = h;
  } else if (b < 128) {
    int tile = b - 64;                      // 0..63
    int bi = tile >> 3, bj = tile & 7;
    int sub = tid >> 8, t256 = tid & 255;
    int ty = t256 >> 4, tx = t256 & 15;
    int i = bi * 16 + ty, j = bj * 16 + tx;
    const float* Ai = (i < RANK) ? (U + i) : (V + (i - RANK));
    const float* Aj = (j < RANK) ? (U + j) : (V + (j - RANK));
    int k0 = sub * 1024;
    float p0 = 0.f, p1 = 0.f, p2 = 0.f, p3 = 0.f;
#pragma unroll 4
    for (int k = k0; k < k0 + 1024; k += 4) {
      p0 += Ai[(size_t)k * RANK]       * Aj[(size_t)k * RANK];
      p1 += Ai[(size_t)(k + 1) * RANK] * Aj[(size_t)(k + 1) * RANK];
      p2 += Ai[(size_t)(k + 2) * RANK] * Aj[(size_t)(k + 2) * RANK];
      p3 += Ai[(size_t)(k + 3) * RANK] * Aj[(size_t)(k + 3) * RANK];
    }
    red[tid] = (p0 + p1) + (p2 + p3);
    __syncthreads();
    if (sub == 0) {
      float s = red[t256] + red[256 + t256];
      if (i < RANK) G[(i + RANK) * R2 + j] = -s;
      else          G[(i - RANK) * R2 + j] =  s;
    }
  } else {
    // Mrf chunk CI = (t_*4 + J)*64 + lg*16 + lr holds M[t_*16+lr][J*32+lg*8+e]
    int CI = (b - 128) * 512 + tid;         // 0..32767
    int lane = CI & 63, rest = CI >> 6;
    int lr = lane & 15, lg = lane >> 4;
    int J = rest & 3, t_ = rest >> 2;
    int i = t_ * 16 + lr, j0 = J * 32 + lg * 8;
    const float* src = (j0 < RANK) ? (U + (size_t)i * RANK + j0)
                                   : (V + (size_t)i * RANK + (j0 - RANK));
    float4 f0 = *(const float4*)src, f1 = *(const float4*)(src + 4);
    u16x8 h;
    h[0] = f2bf(f0.x); h[1] = f2bf(f0.y); h[2] = f2bf(f0.z); h[3] = f2bf(f0.w);
    h[4] = f2bf(f1.x); h[5] = f2bf(f1.y); h[6] = f2bf(f1.z); h[7] = f2bf(f1.w);
    *(u16x8*)(Mrf + (size_t)CI * 8) = h;
  }
}

// ---- 2) generic small 128x128 GEMM launch ----
struct SOp { const float* A; const float* B; float* O; unsigned short* Obf; float a, b; };
struct SOps { SOp op[3]; };
__global__ void k_small(SOps ops) {
  SOp o = ops.op[blockIdx.x >> 6];     // 64 blocks per op
  smallGemm(o.A, o.B, o.O, o.Obf, o.a, o.b, blockIdx.x & 63, threadIdx.x);
}

// ---- 3) k_T1: T1bf = bf16(input @ M). 1024 blocks of 16 rows + 64 G2-blocks.
// (verified R12 code)
__global__ __launch_bounds__(256, 3) void k_T1(const float* __restrict__ input,
                                               const unsigned short* __restrict__ Mf,
                                               unsigned short* __restrict__ T1bf,
                                               const float* __restrict__ G,
                                               float* __restrict__ G2) {
  __shared__ __align__(16) unsigned char lds[33792]; // abuf[w][2] 4KB x8 (32KB) / rbuf [4][16][132] f32 overlay
  if (blockIdx.x >= 1024) {                  // s1 fold: G2 = G*G
    smallGemm(G, G, G2, nullptr, 0.f, 0.f, blockIdx.x - 1024, threadIdx.x);
    return;
  }
  const int tid = threadIdx.x, lane = tid & 63, w = tid >> 6;
  const int lr = lane & 15, lg = lane >> 4;
  const int row0 = blockIdx.x * 16;
  unsigned char* ab0 = lds + w * 8192;

  f32x4 acc[8] = {};
  const float* gbase = input + (size_t)row0 * NIN + w * 512;
  const int Jbase = w * 16;
  float4 s0[4], s1[4];
  bf16x8 bx[8], by[8];

#define T1_SLOAD(KT)                                                          \
  _Pragma("unroll") for (int c = 0; c < 4; ++c) {                             \
    int id = c * 64 + lane; int r = id >> 4, C = id & 15;                     \
    const float* g = gbase + (size_t)r * NIN + (KT) * 128 + C * 8;            \
    s0[c] = *(const float4*)g; s1[c] = *(const float4*)(g + 4);               \
  }
#define T1_SWRITE(BUF)                                                        \
  _Pragma("unroll") for (int c = 0; c < 4; ++c) {                             \
    int id = c * 64 + lane; int r = id >> 4, C = id & 15;                     \
    u16x8 h;                                                                  \
    h[0] = f2bf(s0[c].x); h[1] = f2bf(s0[c].y);                               \
    h[2] = f2bf(s0[c].z); h[3] = f2bf(s0[c].w);                               \
    h[4] = f2bf(s1[c].x); h[5] = f2bf(s1[c].y);                               \
    h[6] = f2bf(s1[c].z); h[7] = f2bf(s1[c].w);                               \
    *(u16x8*)(ab0 + (BUF) * 4096 + r * 256 + ((C ^ (r & 7)) << 4)) = h;       \
  }
#define T1_BLOAD(P, S)                                                        \
  _Pragma("unroll") for (int t = 0; t < 8; ++t)                               \
    P[t] = *(const bf16x8*)(Mf + ((size_t)(t * 64 + Jbase + (S)) * 64 + lane) * 8);

  T1_SLOAD(0);
  T1_SWRITE(0);
  T1_BLOAD(bx, 0);
#pragma unroll
  for (int s = 0; s < 16; ++s) {
    const int kt = s >> 2, sub = s & 3, buf = kt & 1;
    if (sub == 0 && kt < 3) { T1_SLOAD(kt + 1); }
    bf16x8 a = *(const bf16x8*)(ab0 + buf * 4096 + lr * 256 + (((sub * 4 + lg) ^ (lr & 7)) << 4));
    if (s < 15) { if (s & 1) { T1_BLOAD(bx, s + 1); } else { T1_BLOAD(by, s + 1); } }
#pragma unroll
    for (int t = 0; t < 8; ++t) {
      bf16x8 bcur = (s & 1) ? by[t] : bx[t];
      acc[t] = __builtin_amdgcn_mfma_f32_16x16x32_bf16(a, bcur, acc[t], 0, 0, 0);
    }
    if (sub == 2 && kt < 3) { T1_SWRITE(buf ^ 1); }
  }

  __syncthreads();                           // all waves done with their abuf
  float* rbw = (float*)lds + (size_t)w * 2112;
#pragma unroll
  for (int t = 0; t < 8; ++t) {
    int col = t * 16 + lr;
#pragma unroll
    for (int e = 0; e < 4; ++e) rbw[(lg * 4 + e) * 132 + col] = acc[t][e];
  }
  __syncthreads();
  {
    int r = tid >> 4, c8 = tid & 15;
    f32x4 a0 = {}, a1 = {};
#pragma unroll
    for (int ww = 0; ww < 4; ++ww) {
      const float* p = (const float*)lds + (size_t)ww * 2112 + r * 132 + c8 * 8;
      a0 += *(const f32x4*)p;
      a1 += *(const f32x4*)(p + 4);
    }
    u16x8 o;
#pragma unroll
    for (int i = 0; i < 4; ++i) { o[i] = f2bf(a0[i]); o[4 + i] = f2bf(a1[i]); }
    *(u16x8*)(T1bf + (size_t)(row0 + r) * R2 + c8 * 8) = o;
  }
}

// ---- 4) k_OUT: out = input + T2 @ M^T, T2 = T1 @ C^T, with C computed in-block
// from H124, G7, G8tf:  2H - G15 = 2*H124 + (2*H124 - G7)*G8.
// Per wave: E-tiles for its OWN kc rows -> private cbuf region -> T2 (prologue B).
// 512 blocks x 256 thr; LDS 43008 unchanged; 3 blocks/CU.
__global__ __launch_bounds__(256, 3) void k_OUT(const float* __restrict__ input,
                                                const unsigned short* __restrict__ T1bf,
                                                const float* __restrict__ H124,
                                                const float* __restrict__ G7,
                                                const unsigned short* __restrict__ g8tf,
                                                const unsigned short* __restrict__ Mrf,
                                                float* __restrict__ out) {
  __shared__ __align__(16) unsigned char lds[43008];
  unsigned char* cbuf = lds;
  unsigned char* t2buf = lds + 34816;
  const int tid = threadIdx.x, lane = tid & 63, w = tid >> 6;
  const int lr = lane & 15, lg = lane >> 4;
  const int row0 = blockIdx.x * 32;

  // T1 frags (B operand of T2-mfma): lane lr -> T1 row row0+R*16+lr
  bf16x8 t1f[2][4];
#pragma unroll
  for (int R = 0; R < 2; ++R)
#pragma unroll
    for (int J = 0; J < 4; ++J)
      t1f[R][J] = *(const bf16x8*)(T1bf + (size_t)(row0 + R * 16 + lr) * R2 + J * 32 + lg * 8);

  // ---- prologue P1: C rows for wave's kc range (s4 fold) ----
#pragma unroll
  for (int kk = 0; kk < 2; ++kk) {
    int kct = w * 2 + kk;
    int krow = kct * 16 + lr;
    // B-frags: Q row krow, Q = 2*H124 - G7  (built from fp32 global, L2-hot)
    bf16x8 qf[4];
#pragma unroll
    for (int ms = 0; ms < 4; ++ms) {
      int m0 = ms * 32 + lg * 8;
      const float* hp = H124 + (size_t)krow * R2 + m0;
      const float* gp = G7   + (size_t)krow * R2 + m0;
      float4 h0 = *(const float4*)hp, h1 = *(const float4*)(hp + 4);
      float4 g0 = *(const float4*)gp, g1 = *(const float4*)(gp + 4);
      u16x8 qv;
      qv[0] = f2bf(2.f * h0.x - g0.x); qv[1] = f2bf(2.f * h0.y - g0.y);
      qv[2] = f2bf(2.f * h0.z - g0.z); qv[3] = f2bf(2.f * h0.w - g0.w);
      qv[4] = f2bf(2.f * h1.x - g1.x); qv[5] = f2bf(2.f * h1.y - g1.y);
      qv[6] = f2bf(2.f * h1.z - g1.z); qv[7] = f2bf(2.f * h1.w - g1.w);
      qf[ms] = __builtin_bit_cast(bf16x8, qv);
    }
    // E[krow][j] = (Q*G8)[krow][j]; A-frag = G8^T row j from g8tf (frag-order)
#pragma unroll
    for (int jt = 0; jt < 8; ++jt) {
      f32x4 a = {};
#pragma unroll
      for (int ms = 0; ms < 4; ++ms) {
        bf16x8 gfr = *(const bf16x8*)(g8tf + ((size_t)(jt * 4 + ms) * 64 + lane) * 8);
        a = __builtin_amdgcn_mfma_f32_16x16x32_bf16(gfr, qf[ms], a, 0, 0, 0);
      }
      // E_full = 2*H124[krow][j] + a;  C[krow][j'] = sgn * E_full,  j' = j^64
      int j0 = jt * 16 + lg * 4;
      float4 h = *(const float4*)(H124 + (size_t)krow * R2 + j0);
      float sgn = (j0 >= RANK) ? -1.f : 1.f;    // sgn(j') with j' = j0^64
      ushort4 p;
      p.x = f2bf(sgn * (a[0] + 2.f * h.x));
      p.y = f2bf(sgn * (a[1] + 2.f * h.y));
      p.z = f2bf(sgn * (a[2] + 2.f * h.z));
      p.w = f2bf(sgn * (a[3] + 2.f * h.w));
      int gran = (jt * 2 + (lg >> 1)) ^ 8;      // (j0^64)>>3
      int off = (lg & 1) * 8;
      *(ushort4*)(cbuf + krow * 256 + ((gran ^ (krow & 7)) << 4) + off) = p;
    }
  }
  __syncthreads();                           // cbuf ready (per-wave private, but be safe)

  // ---- prologue B: T2[r][kc] = sum_j T1[r][j] C[kc][j]; wave w: kc-tiles {2w,2w+1} ----
#pragma unroll
  for (int kk = 0; kk < 2; ++kk) {
    int kct = w * 2 + kk;
    int kc = kct * 16 + lr;                  // C row this lane supplies
    f32x4 a2[2] = {};
#pragma unroll
    for (int jkt = 0; jkt < 4; ++jkt) {
      bf16x8 cf = *(const bf16x8*)(cbuf + kc * 256 + (((jkt * 4 + lg) ^ (kc & 7)) << 4));
#pragma unroll
      for (int R = 0; R < 2; ++R)
        a2[R] = __builtin_amdgcn_mfma_f32_16x16x32_bf16(cf, t1f[R][jkt], a2[R], 0, 0, 0);
    }
    // acc layout: col=lr -> r_local, row=lg*4+e -> kc = kct*16+lg*4+e
#pragma unroll
    for (int R = 0; R < 2; ++R) {
      int r = R * 16 + lr;
      ushort4 p;
      p.x = f2bf(a2[R][0]); p.y = f2bf(a2[R][1]);
      p.z = f2bf(a2[R][2]); p.w = f2bf(a2[R][3]);
      int gran = kct * 2 + (lg >> 1), off = (lg & 1) * 8;
      *(ushort4*)(t2buf + r * 256 + ((gran ^ (r & 7)) << 4) + off) = p;
    }
  }
  __syncthreads();                           // t2buf ready; cbuf dead (obuf may overlay)

  // bq = T2 frags: lane lr -> row R*16+lr, k-slice J*32+lg*8
  bf16x8 bq[2][4];
#pragma unroll
  for (int R = 0; R < 2; ++R)
#pragma unroll
    for (int J = 0; J < 4; ++J) {
      int row = R * 16 + lr;
      bq[R][J] = *(const bf16x8*)(t2buf + row * 256 + (((J * 4 + lg) ^ (row & 7)) << 4));
    }

  // ---- main loop: verified epilogue shape (64-col groups, [32][68] obuf) ----
  float* obufw = (float*)(lds + w * 8704);   // per-wave [32][68] f32
  bf16x8 xd[4], yd[4];
#define O_DLOAD(P, TTI)                                                       \
  _Pragma("unroll") for (int J = 0; J < 4; ++J)                               \
    P[J] = *(const bf16x8*)(Mrf + ((size_t)((w * 32 + (TTI)) * 4 + J) * 64 + lane) * 8);

  O_DLOAD(xd, 0);
#pragma unroll
  for (int g = 0; g < 8; ++g) {
#pragma unroll
    for (int tt = 0; tt < 4; ++tt) {
      const int tti = g * 4 + tt;
      if (tti < 31) { if (tti & 1) { O_DLOAD(xd, tti + 1); } else { O_DLOAD(yd, tti + 1); } }
#pragma unroll
      for (int R = 0; R < 2; ++R) {
        f32x4 o = {};
#pragma unroll
        for (int J = 0; J < 4; ++J) {
          bf16x8 d = (tti & 1) ? yd[J] : xd[J];
          o = __builtin_amdgcn_mfma_f32_16x16x32_bf16(d, bq[R][J], o, 0, 0, 0);
        }
        *(f32x4*)&obufw[(R * 16 + lr) * 68 + tt * 16 + lg * 4] = o;
      }
    }
#pragma unroll
    for (int c = 0; c < 8; ++c) {
      int id = c * 64 + lane, r = id >> 4, cc = id & 15;
      f32x4 v = *(const f32x4*)&obufw[r * 68 + cc * 4];
      int grow = row0 + r, gcol = w * 512 + g * 64 + cc * 4;
      float4 inv = *(const float4*)(input + (size_t)grow * NIN + gcol);
      float4 res = { v[0] + inv.x, v[1] + inv.y, v[2] + inv.z, v[3] + inv.w };
      *(float4*)(out + (size_t)grow * NIN + gcol) = res;
    }
  }
}

extern "C" void kernel_launch(void* const* d_in, const int* in_sizes, int n_in,
                              void* d_out, int out_size, void* d_ws, size_t ws_size,
                              hipStream_t stream) {
  const float* input = (const float*)d_in[0];
  const float* U     = (const float*)d_in[1];
  const float* V     = (const float*)d_in[2];
  float* out = (float*)d_out;
  char* ws = (char*)d_ws;

  // workspace layout
  float* mats = (float*)ws;                       // 10 x 128x128 fp32 = 640 KB
  float* G   = mats + 0 * 16384;
  float* G2  = mats + 1 * 16384;
  float* G3  = mats + 2 * 16384;
  float* G4  = mats + 3 * 16384;
  float* G7  = mats + 4 * 16384;
  float* G8  = mats + 5 * 16384;
  float* H12 = mats + 6 * 16384;
  float* H124= mats + 7 * 16384;
  unsigned short* Mf   = (unsigned short*)(ws + 10 * 65536);              // 512 KB frag-order M (K=2048)
  unsigned short* Mrf  = (unsigned short*)(ws + 10 * 65536 + 524288);     // 512 KB frag-order M rows (K=128)
  unsigned short* T1bf = (unsigned short*)(ws + 10 * 65536 + 2 * 524288); // 4 MB
  unsigned short* G8tf = (unsigned short*)(ws + 10 * 65536 + 2 * 524288 + 4194304); // 32 KB G8^T frag-order

  k_prep<<<192, 512, 0, stream>>>(U, V, Mf, Mrf, G);
  k_T1<<<1088, 256, 0, stream>>>(input, Mf, T1bf, G, G2);   // + s1 fold (G2)

  { SOps o = {{ {G2, G2, G4, nullptr, 0.f, 0.f}, {G2, G, G3, nullptr, 0.f, 0.f}, {G, G2, H12, nullptr, 1.f, 1.f} }};
    k_small<<<192, 256, 0, stream>>>(o); }
  { SOps o = {{ {G4, G4, G8, G8tf, 0.f, 0.f}, {G3, G4, G7, nullptr, 0.f, 0.f}, {H12, G4, H124, nullptr, 0.f, 1.f} }};
    k_small<<<192, 256, 0, stream>>>(o); }

  k_OUT<<<512, 256, 0, stream>>>(input, T1bf, H124, G7, G8tf, Mrf, out);
}

// Round 16
// 137.163 us; speedup vs baseline: 1.3849x; 1.0873x over previous
//
#include <hip/hip_runtime.h>
#include <hip/hip_bf16.h>
#include <cstdint>
#include <cstddef>

// ---- problem constants ----
#define NIN   2048
#define RANK  64
#define R2    128      // 2*RANK
#define NROWS 16384    // 8*2048 flattened batch*seq rows

typedef __bf16 bf16x8 __attribute__((ext_vector_type(8)));
typedef float  f32x4  __attribute__((ext_vector_type(4)));
typedef unsigned short u16x8 __attribute__((ext_vector_type(8)));

__device__ __forceinline__ unsigned short f2bf(float f) {
  union { float f; unsigned u; } x; x.f = f;
  return (unsigned short)((x.u + 0x7fffu + ((x.u >> 16) & 1u)) >> 16);
}

// ---- small GEMM tile helper: 16x16 tile t of (A + a*I)(B + b*I), fp32 ----
__device__ __forceinline__ void smallGemm(const float* __restrict__ A,
                                          const float* __restrict__ B,
                                          float* __restrict__ O,
                                          float a, float b, int t, int tid) {
  int i = (t >> 3) * 16 + (tid >> 4);
  int j = (t & 7) * 16 + (tid & 15);
  float acc = 0.f;
#pragma unroll 8
  for (int k = 0; k < R2; ++k) {
    float av = A[i * R2 + k]; if (k == i) av += a;
    float bv = B[k * R2 + j]; if (k == j) bv += b;
    acc += av * bv;
  }
  O[i * R2 + j] = acc;
}

// ---- 1) k_prep: 192 blocks x 512 thr.
//  blocks 0..63:   Mf (frag-order over K=2048; B-operand of k_T1)
//  blocks 64..127: G = J*(M^T M) tile, 2-way K-split + LDS reduce, 4 accumulators
//  blocks 128..191: Mrf (M rows in frag-order; A-operand of k_OUT)
__global__ __launch_bounds__(512) void k_prep(const float* __restrict__ U,
                                              const float* __restrict__ V,
                                              unsigned short* __restrict__ Mf,
                                              unsigned short* __restrict__ Mrf,
                                              float* __restrict__ G) {
  __shared__ float red[512];
  int b = blockIdx.x, tid = threadIdx.x;
  if (b < 64) {
    int CI = b * 512 + tid;                 // 0..32767
    int lane = CI & 63, J = (CI >> 6) & 63, t = CI >> 12;
    int n = t * 16 + (lane & 15);
    int k0 = J * 32 + (lane >> 4) * 8;
    const float* src = (n < RANK) ? (U + n) : (V + (n - RANK));
    u16x8 h;
#pragma unroll
    for (int e = 0; e < 8; ++e) h[e] = f2bf(src[(size_t)(k0 + e) * RANK]);
    *(u16x8*)(Mf + (size_t)CI * 8) = h;
  } else if (b < 128) {
    int tile = b - 64;                      // 0..63
    int bi = tile >> 3, bj = tile & 7;
    int sub = tid >> 8, t256 = tid & 255;
    int ty = t256 >> 4, tx = t256 & 15;
    int i = bi * 16 + ty, j = bj * 16 + tx;
    const float* Ai = (i < RANK) ? (U + i) : (V + (i - RANK));
    const float* Aj = (j < RANK) ? (U + j) : (V + (j - RANK));
    int k0 = sub * 1024;
    float p0 = 0.f, p1 = 0.f, p2 = 0.f, p3 = 0.f;
#pragma unroll 4
    for (int k = k0; k < k0 + 1024; k += 4) {
      p0 += Ai[(size_t)k * RANK]       * Aj[(size_t)k * RANK];
      p1 += Ai[(size_t)(k + 1) * RANK] * Aj[(size_t)(k + 1) * RANK];
      p2 += Ai[(size_t)(k + 2) * RANK] * Aj[(size_t)(k + 2) * RANK];
      p3 += Ai[(size_t)(k + 3) * RANK] * Aj[(size_t)(k + 3) * RANK];
    }
    red[tid] = (p0 + p1) + (p2 + p3);
    __syncthreads();
    if (sub == 0) {
      float s = red[t256] + red[256 + t256];
      if (i < RANK) G[(i + RANK) * R2 + j] = -s;
      else          G[(i - RANK) * R2 + j] =  s;
    }
  } else {
    // Mrf chunk CI = (t_*4 + J)*64 + lg*16 + lr holds M[t_*16+lr][J*32+lg*8+e]
    int CI = (b - 128) * 512 + tid;         // 0..32767
    int lane = CI & 63, rest = CI >> 6;
    int lr = lane & 15, lg = lane >> 4;
    int J = rest & 3, t_ = rest >> 2;
    int i = t_ * 16 + lr, j0 = J * 32 + lg * 8;
    const float* src = (j0 < RANK) ? (U + (size_t)i * RANK + j0)
                                   : (V + (size_t)i * RANK + (j0 - RANK));
    float4 f0 = *(const float4*)src, f1 = *(const float4*)(src + 4);
    u16x8 h;
    h[0] = f2bf(f0.x); h[1] = f2bf(f0.y); h[2] = f2bf(f0.z); h[3] = f2bf(f0.w);
    h[4] = f2bf(f1.x); h[5] = f2bf(f1.y); h[6] = f2bf(f1.z); h[7] = f2bf(f1.w);
    *(u16x8*)(Mrf + (size_t)CI * 8) = h;
  }
}

// ---- 2) generic small 128x128 GEMM launch: O = (A + a*I)(B + b*I), fp32 ----
struct SOp { const float* A; const float* B; float* O; float a, b; };
struct SOps { SOp op[3]; };
__global__ void k_small(SOps ops) {
  SOp o = ops.op[blockIdx.x >> 6];     // 64 blocks per op
  smallGemm(o.A, o.B, o.O, o.a, o.b, blockIdx.x & 63, threadIdx.x);
}

// ---- 3) k_T1: T1bf = bf16(input @ M), 512 blocks of 32 rows + 64 G2-blocks.
// Wave w owns K-range [w*512,(w+1)*512). Input staged via per-wave swizzled LDS;
// M frags contiguous from Mf. Two-pass 16-row reduce epilogue keeps LDS at 36.9KB.
// Blocks >=512: G2 = G*G fold.
__global__ __launch_bounds__(256) void k_T1(const float* __restrict__ input,
                                            const unsigned short* __restrict__ Mf,
                                            unsigned short* __restrict__ T1bf,
                                            const float* __restrict__ G,
                                            float* __restrict__ G2) {
  __shared__ __align__(16) unsigned char lds[36864];  // abuf[w] 8KB x4 (32KB) / rbuf [4][18][128] f32 overlay
  if (blockIdx.x >= 512) {                  // s1 fold: G2 = G*G
    smallGemm(G, G, G2, 0.f, 0.f, blockIdx.x - 512, threadIdx.x);
    return;
  }
  const int tid = threadIdx.x, lane = tid & 63, w = tid >> 6;
  const int lr = lane & 15, lg = lane >> 4;
  const int row0 = blockIdx.x * 32;
  unsigned char* abuf = lds + w * 8192;

  f32x4 acc[2][8] = {};
  const float* gbase = input + (size_t)row0 * NIN + w * 512;
  const int Jbase = w * 16;
  float4 s0[8], s1[8];
  bf16x8 bx[8], by[8];

#define T1_SLOAD(KT)                                                          \
  _Pragma("unroll") for (int p = 0; p < 8; ++p) {                             \
    int id = p * 64 + lane; int r = id >> 4, C = id & 15;                     \
    const float* g = gbase + (size_t)r * NIN + (KT) * 128 + C * 8;            \
    s0[p] = *(const float4*)g; s1[p] = *(const float4*)(g + 4);               \
  }
#define T1_SWRITE()                                                           \
  _Pragma("unroll") for (int p = 0; p < 8; ++p) {                             \
    int id = p * 64 + lane; int r = id >> 4, C = id & 15;                     \
    u16x8 h;                                                                  \
    h[0] = f2bf(s0[p].x); h[1] = f2bf(s0[p].y);                               \
    h[2] = f2bf(s0[p].z); h[3] = f2bf(s0[p].w);                               \
    h[4] = f2bf(s1[p].x); h[5] = f2bf(s1[p].y);                               \
    h[6] = f2bf(s1[p].z); h[7] = f2bf(s1[p].w);                               \
    *(u16x8*)(abuf + r * 256 + ((C ^ (r & 7)) << 4)) = h;                     \
  }
#define T1_BLOAD(P, S)                                                        \
  _Pragma("unroll") for (int t = 0; t < 8; ++t)                               \
    P[t] = *(const bf16x8*)(Mf + ((size_t)(t * 64 + Jbase + (S)) * 64 + lane) * 8);

  T1_SLOAD(0);
  T1_SWRITE();
  T1_BLOAD(bx, 0);
#pragma unroll
  for (int s = 0; s < 16; ++s) {
    const int kt = s >> 2, j = s & 3;
    if (j == 0 && kt < 3) { T1_SLOAD(kt + 1); }
    bf16x8 a0, a1;
    {
      int C = j * 4 + lg;
      a0 = *(const bf16x8*)(abuf + lr * 256 + ((C ^ (lr & 7)) << 4));
      a1 = *(const bf16x8*)(abuf + (16 + lr) * 256 + ((C ^ ((16 + lr) & 7)) << 4));
    }
    if (s < 15) { if (s & 1) { T1_BLOAD(bx, s + 1); } else { T1_BLOAD(by, s + 1); } }
#pragma unroll
    for (int t = 0; t < 8; ++t) {
      bf16x8 bcur = (s & 1) ? by[t] : bx[t];
      acc[0][t] = __builtin_amdgcn_mfma_f32_16x16x32_bf16(a0, bcur, acc[0][t], 0, 0, 0);
      acc[1][t] = __builtin_amdgcn_mfma_f32_16x16x32_bf16(a1, bcur, acc[1][t], 0, 0, 0);
    }
    if (j == 3 && kt < 3) { T1_SWRITE(); }
  }

  // ---- two-pass reduce epilogue: rbuf [4][18 rows][128 cols] f32 (rows 16+2 pad) ----
  float* rbw = (float*)lds + (size_t)w * 2304;      // 18*128 floats per wave
#pragma unroll
  for (int m = 0; m < 2; ++m) {
    __syncthreads();                                // (m=0: abuf done) / (m=1: reduce reads done)
#pragma unroll
    for (int t = 0; t < 8; ++t) {
      int col = t * 16 + lr;
#pragma unroll
      for (int e = 0; e < 4; ++e) rbw[(lg * 4 + e) * 128 + col] = acc[m][t][e];
    }
    __syncthreads();
    {
      int r = tid >> 4, cg = tid & 15;              // row r (0..15), cols cg*8..+8
      f32x4 a0 = {}, a1 = {};
#pragma unroll
      for (int ww = 0; ww < 4; ++ww) {
        const float* p = (const float*)lds + (size_t)ww * 2304 + r * 128 + cg * 8;
        a0 += *(const f32x4*)p;
        a1 += *(const f32x4*)(p + 4);
      }
      u16x8 o;
#pragma unroll
      for (int i = 0; i < 4; ++i) { o[i] = f2bf(a0[i]); o[4 + i] = f2bf(a1[i]); }
      *(u16x8*)(T1bf + (size_t)(row0 + m * 16 + r) * R2 + cg * 8) = o;
    }
  }
}

// ---- 4) k_OUT: out = input + T2 @ M^T, with T2 = T1 @ C^T computed in-block.
// C[k][j] = sgn(j)*(2H - G15)[k][jj(j)]. 512 blocks x 256 thr; 32 rows x 2048 cols.
// Wave w owns cols [w*512,(w+1)*512). LDS 43008: cbuf 32KB (prologue) overlaid by
// obuf 4x[32][68] f32 (main); t2buf bf16 [32][128] swz at 34816. 3 blocks/CU.
__global__ __launch_bounds__(256) void k_OUT(const float* __restrict__ input,
                                             const unsigned short* __restrict__ T1bf,
                                             const float* __restrict__ Hm,
                                             const float* __restrict__ G15m,
                                             const unsigned short* __restrict__ Mrf,
                                             float* __restrict__ out) {
  __shared__ __align__(16) unsigned char lds[43008];
  unsigned char* cbuf = lds;
  unsigned char* t2buf = lds + 34816;
  const int tid = threadIdx.x, lane = tid & 63, w = tid >> 6;
  const int lr = lane & 15, lg = lane >> 4;
  const int row0 = blockIdx.x * 32;

  // ---- prologue A: cbuf[k][j-granule swz] = C row-major bf16 ----
#pragma unroll
  for (int it = 0; it < 8; ++it) {
    int id = it * 256 + tid;                 // chunk 0..2047
    int k = id >> 4, j8 = id & 15, j0 = j8 * 8;
    int jj0 = (j0 < RANK) ? j0 + RANK : j0 - RANK;
    float sgn = (j0 < RANK) ? -1.f : 1.f;
    const float* hp = Hm + k * R2 + jj0;
    const float* gp = G15m + k * R2 + jj0;
    float4 h0 = *(const float4*)hp, h1 = *(const float4*)(hp + 4);
    float4 g0 = *(const float4*)gp, g1 = *(const float4*)(gp + 4);
    u16x8 cv;
    cv[0] = f2bf(sgn * (2.f * h0.x - g0.x));
    cv[1] = f2bf(sgn * (2.f * h0.y - g0.y));
    cv[2] = f2bf(sgn * (2.f * h0.z - g0.z));
    cv[3] = f2bf(sgn * (2.f * h0.w - g0.w));
    cv[4] = f2bf(sgn * (2.f * h1.x - g1.x));
    cv[5] = f2bf(sgn * (2.f * h1.y - g1.y));
    cv[6] = f2bf(sgn * (2.f * h1.z - g1.z));
    cv[7] = f2bf(sgn * (2.f * h1.w - g1.w));
    *(u16x8*)(cbuf + k * 256 + ((j8 ^ (k & 7)) << 4)) = cv;
  }
  // T1 frags (B operand of T2-mfma): lane lr -> T1 row row0+R*16+lr
  bf16x8 t1f[2][4];
#pragma unroll
  for (int R = 0; R < 2; ++R)
#pragma unroll
    for (int J = 0; J < 4; ++J)
      t1f[R][J] = *(const bf16x8*)(T1bf + (size_t)(row0 + R * 16 + lr) * R2 + J * 32 + lg * 8);
  __syncthreads();                           // cbuf ready

  // ---- prologue B: T2[r][kc] = sum_j T1[r][j] C[kc][j]; wave w: kc-tiles {2w,2w+1} ----
#pragma unroll
  for (int kk = 0; kk < 2; ++kk) {
    int kct = w * 2 + kk;
    int kc = kct * 16 + lr;                  // C row this lane supplies
    f32x4 a2[2] = {};
#pragma unroll
    for (int jkt = 0; jkt < 4; ++jkt) {
      bf16x8 cf = *(const bf16x8*)(cbuf + kc * 256 + (((jkt * 4 + lg) ^ (kc & 7)) << 4));
#pragma unroll
      for (int R = 0; R < 2; ++R)
        a2[R] = __builtin_amdgcn_mfma_f32_16x16x32_bf16(cf, t1f[R][jkt], a2[R], 0, 0, 0);
    }
    // acc layout: col=lr -> r_local, row=lg*4+e -> kc = kct*16+lg*4+e
#pragma unroll
    for (int R = 0; R < 2; ++R) {
      int r = R * 16 + lr;
      ushort4 p;
      p.x = f2bf(a2[R][0]); p.y = f2bf(a2[R][1]);
      p.z = f2bf(a2[R][2]); p.w = f2bf(a2[R][3]);
      int gran = kct * 2 + (lg >> 1), off = (lg & 1) * 8;
      *(ushort4*)(t2buf + r * 256 + ((gran ^ (r & 7)) << 4) + off) = p;
    }
  }
  __syncthreads();                           // t2buf ready; cbuf dead (obuf may overlay)

  // bq = T2 frags: lane lr -> row R*16+lr, k-slice J*32+lg*8
  bf16x8 bq[2][4];
#pragma unroll
  for (int R = 0; R < 2; ++R)
#pragma unroll
    for (int J = 0; J < 4; ++J) {
      int row = R * 16 + lr;
      bq[R][J] = *(const bf16x8*)(t2buf + row * 256 + (((J * 4 + lg) ^ (row & 7)) << 4));
    }

  // ---- main loop: verified epilogue shape (64-col groups, [32][68] obuf) ----
  float* obufw = (float*)(lds + w * 8704);   // per-wave [32][68] f32
  bf16x8 xd[4], yd[4];
#define O_DLOAD(P, TTI)                                                       \
  _Pragma("unroll") for (int J = 0; J < 4; ++J)                               \
    P[J] = *(const bf16x8*)(Mrf + ((size_t)((w * 32 + (TTI)) * 4 + J) * 64 + lane) * 8);

  O_DLOAD(xd, 0);
#pragma unroll
  for (int g = 0; g < 8; ++g) {
#pragma unroll
    for (int tt = 0; tt < 4; ++tt) {
      const int tti = g * 4 + tt;
      if (tti < 31) { if (tti & 1) { O_DLOAD(xd, tti + 1); } else { O_DLOAD(yd, tti + 1); } }
#pragma unroll
      for (int R = 0; R < 2; ++R) {
        f32x4 o = {};
#pragma unroll
        for (int J = 0; J < 4; ++J) {
          bf16x8 d = (tti & 1) ? yd[J] : xd[J];
          o = __builtin_amdgcn_mfma_f32_16x16x32_bf16(d, bq[R][J], o, 0, 0, 0);
        }
        *(f32x4*)&obufw[(R * 16 + lr) * 68 + tt * 16 + lg * 4] = o;
      }
    }
#pragma unroll
    for (int c = 0; c < 8; ++c) {
      int id = c * 64 + lane, r = id >> 4, cc = id & 15;
      f32x4 v = *(const f32x4*)&obufw[r * 68 + cc * 4];
      int grow = row0 + r, gcol = w * 512 + g * 64 + cc * 4;
      float4 inv = *(const float4*)(input + (size_t)grow * NIN + gcol);
      float4 res = { v[0] + inv.x, v[1] + inv.y, v[2] + inv.z, v[3] + inv.w };
      *(float4*)(out + (size_t)grow * NIN + gcol) = res;
    }
  }
}

extern "C" void kernel_launch(void* const* d_in, const int* in_sizes, int n_in,
                              void* d_out, int out_size, void* d_ws, size_t ws_size,
                              hipStream_t stream) {
  const float* input = (const float*)d_in[0];
  const float* U     = (const float*)d_in[1];
  const float* V     = (const float*)d_in[2];
  float* out = (float*)d_out;
  char* ws = (char*)d_ws;

  // workspace layout
  float* mats = (float*)ws;                       // 10 x 128x128 fp32 = 640 KB
  float* G   = mats + 0 * 16384;
  float* G2  = mats + 1 * 16384;
  float* G3  = mats + 2 * 16384;
  float* G4  = mats + 3 * 16384;
  float* G7  = mats + 4 * 16384;
  float* G8  = mats + 5 * 16384;
  float* H12 = mats + 6 * 16384;
  float* H124= mats + 7 * 16384;
  float* H   = mats + 8 * 16384;
  float* G15 = mats + 9 * 16384;
  unsigned short* Mf   = (unsigned short*)(ws + 10 * 65536);              // 512 KB frag-order M (K=2048)
  unsigned short* Mrf  = (unsigned short*)(ws + 10 * 65536 + 524288);     // 512 KB frag-order M rows (K=128)
  unsigned short* T1bf = (unsigned short*)(ws + 10 * 65536 + 2 * 524288); // 4 MB

  k_prep<<<192, 512, 0, stream>>>(U, V, Mf, Mrf, G);
  k_T1<<<576, 256, 0, stream>>>(input, Mf, T1bf, G, G2);   // + s1 fold (G2)

  { SOps o = {{ {G2, G2, G4, 0.f, 0.f}, {G2, G, G3, 0.f, 0.f}, {G, G2, H12, 1.f, 1.f} }};
    k_small<<<192, 256, 0, stream>>>(o); }
  { SOps o = {{ {G4, G4, G8, 0.f, 0.f}, {G3, G4, G7, 0.f, 0.f}, {H12, G4, H124, 0.f, 1.f} }};
    k_small<<<192, 256, 0, stream>>>(o); }
  { SOps o = {{ {G7, G8, G15, 0.f, 0.f}, {H124, G8, H, 0.f, 1.f}, {nullptr,nullptr,nullptr,0.f,0.f} }};
    k_small<<<128, 256, 0, stream>>>(o); }

  k_OUT<<<512, 256, 0, stream>>>(input, T1bf, H, G15, Mrf, out);
}